// Round 12
// baseline (125.694 us; speedup 1.0000x reference)
//
#include <hip/hip_runtime.h>
#include <math.h>

#define B_ 4
#define C_ 1024
#define T_ 1024
#define H_ 16
#define CH_ 64
#define BCT (B_ * C_ * T_)   // 4194304

typedef __attribute__((ext_vector_type(8))) short s16x8;   // 8 bf16 (4 VGPRs)
typedef __attribute__((ext_vector_type(4))) float f32x4;
typedef unsigned short u16;

#define MFMA16(a, b, c) __builtin_amdgcn_mfma_f32_16x16x32_bf16((a), (b), (c), 0, 0, 0)

extern "C" __device__ float __ocml_native_exp2_f32(float);

__device__ __forceinline__ u16 f2bf(float f) {
    union { float f; unsigned u; } v; v.f = f;
    unsigned r = (v.u + 0x7fffu + ((v.u >> 16) & 1u)) >> 16;   // RNE
    return (u16)r;
}
__device__ __forceinline__ float bf2f(u16 h) {
    union { unsigned u; float f; } v; v.u = (unsigned)h << 16; return v.f;
}

// async global->LDS, 16B per lane; LDS dest = wave-uniform base + lane*16
typedef __attribute__((address_space(3))) unsigned int lds_u32;
typedef __attribute__((address_space(1))) const unsigned int glb_u32;
__device__ __forceinline__ void glds16(const void* g, const void* l_wave_uniform) {
    __builtin_amdgcn_global_load_lds(
        (glb_u32*)(unsigned long long)g,
        (lds_u32*)(unsigned long long)l_wave_uniform, 16, 0, 0);
}

// counted-vmcnt barrier: keep N loads in flight across the barrier (T4)
#define WAIT_BARRIER(N)                                   \
    asm volatile("s_waitcnt vmcnt(" #N ")" ::: "memory"); \
    __builtin_amdgcn_s_barrier();                         \
    __builtin_amdgcn_sched_barrier(0)

#define BARRIER_ONLY()                                    \
    __builtin_amdgcn_s_barrier();                         \
    __builtin_amdgcn_sched_barrier(0)

// ---------------------------------------------------------------------------
// prep_kernel: lnT (384) + wcvt (2048) + mask_tail (8) in one launch.
// ---------------------------------------------------------------------------
__global__ __launch_bounds__(512) void prep_kernel(
    const float* __restrict__ xq, const float* __restrict__ xk, const float* __restrict__ xv,
    const float* __restrict__ wq3, const float* __restrict__ wk3, const float* __restrict__ wv3,
    const int* __restrict__ qm, const int* __restrict__ kvm,
    const float* __restrict__ qnw, const float* __restrict__ qnb,
    const float* __restrict__ knw, const float* __restrict__ knb,
    const float* __restrict__ vnw, const float* __restrict__ vnb,
    u16* __restrict__ oq, u16* __restrict__ ok, u16* __restrict__ ov,
    const float* __restrict__ w0, const float* __restrict__ w1,
    const float* __restrict__ w2, const float* __restrict__ w3,
    u16* __restrict__ o0, u16* __restrict__ o1, u16* __restrict__ o2, u16* __restrict__ o3,
    float* __restrict__ tail_out, int ntail)
{
    __shared__ __align__(16) u16 tile[32 * 1032];     // [t][c], stride 2064B
    __shared__ float red1[16][33], red2[16][33];
    __shared__ float musL[32], rssL[32];

    const int bid = blockIdx.x;
    if (bid >= 384) {
        if (bid >= 2432) {                              // ---- mask_tail
            int i = (bid - 2432) * 512 + threadIdx.x;
            if (i < ntail) tail_out[i] = (qm[i] != 0) ? 1.f : 0.f;
            return;
        }
        // ---- wcvt: 512 blocks per matrix, 4 floats/thread
        const int b2 = bid - 384;
        const int mat = b2 >> 9;
        const float* __restrict__ w = (mat == 0) ? w0 : (mat == 1) ? w1 : (mat == 2) ? w2 : w3;
        u16* __restrict__ o = (mat == 0) ? o0 : (mat == 1) ? o1 : (mat == 2) ? o2 : o3;
        const int i = ((b2 & 511) * 512 + threadIdx.x) * 4;
        float4 v = *(const float4*)&w[i];
        uint2 p;
        p.x = (unsigned)f2bf(v.x) | ((unsigned)f2bf(v.y) << 16);
        p.y = (unsigned)f2bf(v.z) | ((unsigned)f2bf(v.w) << 16);
        *(uint2*)&o[i] = p;
        return;
    }

    // ---- lnT
    const int z = bid >> 5;                 // tensor*4 + b
    const int tensor = z >> 2, b = z & 3;
    const float* __restrict__ x   = (tensor == 0) ? xq  : (tensor == 1) ? xk  : xv;
    const float* __restrict__ w3c = (tensor == 0) ? wq3 : (tensor == 1) ? wk3 : wv3;
    const int* __restrict__ msk   = (tensor == 0) ? qm  : kvm;
    const float* __restrict__ wln = (tensor == 0) ? qnw : (tensor == 1) ? knw : vnw;
    const float* __restrict__ bln = (tensor == 0) ? qnb : (tensor == 1) ? knb : vnb;
    u16* __restrict__ xt = (tensor == 0) ? oq : (tensor == 1) ? ok : ov;

    const int t0 = (bid & 31) * 32;

    const int tl = threadIdx.x & 31, cs = threadIdx.x >> 5;   // cs 0..15
    const int t = t0 + tl;
    const float mk = (msk[b * T_ + t] != 0) ? 1.f : 0.f;

    float s1 = 0.f, s2 = 0.f;
    #pragma unroll 4
    for (int i = 0; i < 32; ++i) {
        const int c = 2 * (cs + 16 * i);
        const float* xr0 = x + ((size_t)(b * C_ + c)) * T_ + t;
        const float* xr1 = xr0 + T_;
        float xc0 = xr0[0];
        float xm0 = (t > 0)      ? xr0[-1] : 0.f;
        float xp0 = (t < T_ - 1) ? xr0[1]  : 0.f;
        float v0 = (w3c[3 * c + 0] * xm0 + w3c[3 * c + 1] * xc0 + w3c[3 * c + 2] * xp0) * mk;
        float xc1 = xr1[0];
        float xm1 = (t > 0)      ? xr1[-1] : 0.f;
        float xp1 = (t < T_ - 1) ? xr1[1]  : 0.f;
        float v1 = (w3c[3 * c + 3] * xm1 + w3c[3 * c + 4] * xc1 + w3c[3 * c + 5] * xp1) * mk;
        s1 += v0 + v1;
        s2 += v0 * v0 + v1 * v1;
        *(unsigned*)&tile[tl * 1032 + c] =
            (unsigned)f2bf(v0) | ((unsigned)f2bf(v1) << 16);
    }
    red1[cs][tl] = s1;
    red2[cs][tl] = s2;
    __syncthreads();
    if (threadIdx.x < 32) {
        float a = 0.f, q2 = 0.f;
        #pragma unroll
        for (int i = 0; i < 16; ++i) { a += red1[i][threadIdx.x]; q2 += red2[i][threadIdx.x]; }
        float m_  = a  * (1.f / C_);
        float var = q2 * (1.f / C_) - m_ * m_;
        musL[threadIdx.x] = m_;
        rssL[threadIdx.x] = rsqrtf(var + 1e-5f);
    }
    __syncthreads();

    #pragma unroll
    for (int it = 0; it < 8; ++it) {
        const int idx = it * 512 + threadIdx.x;
        const int tt = idx >> 7, c0 = (idx & 127) * 8;
        const s16x8 pv = *(const s16x8*)&tile[tt * 1032 + c0];
        const float m_ = musL[tt], rv = rssL[tt];
        const float4 w0v = *(const float4*)&wln[c0];
        const float4 w1v = *(const float4*)&wln[c0 + 4];
        const float4 b0v = *(const float4*)&bln[c0];
        const float4 b1v = *(const float4*)&bln[c0 + 4];
        uint4 o;
        float f0, f1;
        f0 = (bf2f((u16)pv[0]) - m_) * rv * w0v.x + b0v.x;
        f1 = (bf2f((u16)pv[1]) - m_) * rv * w0v.y + b0v.y;
        o.x = (unsigned)f2bf(f0) | ((unsigned)f2bf(f1) << 16);
        f0 = (bf2f((u16)pv[2]) - m_) * rv * w0v.z + b0v.z;
        f1 = (bf2f((u16)pv[3]) - m_) * rv * w0v.w + b0v.w;
        o.y = (unsigned)f2bf(f0) | ((unsigned)f2bf(f1) << 16);
        f0 = (bf2f((u16)pv[4]) - m_) * rv * w1v.x + b1v.x;
        f1 = (bf2f((u16)pv[5]) - m_) * rv * w1v.y + b1v.y;
        o.z = (unsigned)f2bf(f0) | ((unsigned)f2bf(f1) << 16);
        f0 = (bf2f((u16)pv[6]) - m_) * rv * w1v.z + b1v.z;
        f1 = (bf2f((u16)pv[7]) - m_) * rv * w1v.w + b1v.w;
        o.w = (unsigned)f2bf(f0) | ((unsigned)f2bf(f1) << 16);
        *(uint4*)&xt[((size_t)(b * T_ + t0 + tt)) * C_ + c0] = o;
    }
}

// ---------------------------------------------------------------------------
// gemm_qkv256: 256x256 tile, BK=64, 8 waves (2M x 4N, wave tile 128x64),
// lead-6 counted-vmcnt half-tile pipeline, 2 LDS dbuf (128KB), st_16x32
// swizzle both-sides.  Half-tile stream H = 4*kt + {B0,B1,A0,A1}.
// Stage at phase (kt,q): H = 4kt + q + 6  -> A0,A1(kt+1) @ q0,q1 (inactive
// dbuf), B0,B1(kt+2) @ q2,q3 (active dbuf but regions dead since phase 0).
// Boundary barrier waits vmcnt(4) (kt+1 fully staged; 2 newest halves in
// flight); vmcnt(0) only at kt==14.  2 barriers/phase order stage-writes
// after the previous phase's lgkm-drained reads.
// ---------------------------------------------------------------------------
__global__ __launch_bounds__(512, 2) void gemm_qkv256_kernel(
    const u16* __restrict__ Xq, const u16* __restrict__ Xk, const u16* __restrict__ Xv,
    const u16* __restrict__ Wq, const u16* __restrict__ Wk, const u16* __restrict__ Wv,
    const float* __restrict__ bq, const float* __restrict__ bk, const float* __restrict__ bv,
    u16* __restrict__ Qt, u16* __restrict__ Kt, u16* __restrict__ Vb,
    const int* __restrict__ kvm)
{
    const int p = blockIdx.x;                      // 0..191
    const int lb = (p & 7) * 24 + (p >> 3);        // bijective (192 % 8 == 0)
    const int tensor = lb >> 6, tidx = lb & 63;

    const float qscale = 0.125f * 1.44269504088896340736f;
    const u16 *A, *Bm; u16* Dp; const float* bias; const int* mask;
    float scale; int bias_on_n; long ldd; int m0, n0;
    if (tensor == 0) {
        A = Xq; Bm = Wq; Dp = Qt; bias = bq; mask = nullptr;
        scale = qscale; bias_on_n = 1; ldd = 1024;
        m0 = (tidx >> 2) * 256; n0 = (tidx & 3) * 256;
    } else if (tensor == 1) {
        A = Xk; Bm = Wk; Dp = Kt; bias = bk; mask = nullptr;
        scale = 1.f; bias_on_n = 1; ldd = 1024;
        m0 = (tidx >> 2) * 256; n0 = (tidx & 3) * 256;
    } else {
        A = Wv; Bm = Xv; Dp = Vb; bias = bv; mask = kvm;
        scale = 1.f; bias_on_n = 0; ldd = 4096;
        m0 = (tidx & 3) * 256; n0 = (tidx >> 2) * 256;
    }

    __shared__ __align__(16) u16 LA[2][2][128 * 64];   // [dbuf][half] 64KB
    __shared__ __align__(16) u16 LB[2][2][128 * 64];   // 64KB

    const int tid = threadIdx.x, lane = tid & 63, wave = tid >> 6;
    const int r = lane & 15, g = lane >> 4;
    const int wm = (wave >> 2) * 128;              // 0 or 128
    const int wn = (wave & 3) * 64;                // 0,64,128,192
    const int ha = wave >> 2;                      // A half used by this wave
    const int hb = (wave & 3) >> 1;                // B half used by this wave
    const int rbB = wn & 64;                       // row base inside B half

    const u16* gA = A + (size_t)m0 * 1024;
    const u16* gB = Bm + (size_t)n0 * 1024;
    // st_16x32 source swizzle: LDS row within half = wave*16+i*8+(lane>>3);
    // (row>>2)&1 == (lane>>5)&1 here.
    const int ccsrc = (lane & 7) ^ (((lane >> 5) & 1) << 1);
    const int rsw = ((r >> 2) & 1) << 1;           // read-side XOR on chunk

    auto stageH = [&](int H) {
        const int kt2 = H >> 2, hsel = H & 3;      // 0=B0,1=B1,2=A0,3=A1
        const int isA = hsel >> 1, hh = hsel & 1;
        const u16* gsrc = isA ? gA : gB;
        u16* ldst = isA ? &LA[kt2 & 1][hh][0] : &LB[kt2 & 1][hh][0];
        #pragma unroll
        for (int i = 0; i < 2; ++i) {
            const int rowin = wave * 16 + i * 8;   // +lane>>3 by HW lane offset
            const int row = hh * 128 + rowin + (lane >> 3);
            glds16(gsrc + (size_t)row * 1024 + kt2 * 64 + ccsrc * 8,
                   ldst + rowin * 64);
        }
    };

    f32x4 acc[8][4];
    #pragma unroll
    for (int i = 0; i < 8; ++i)
        #pragma unroll
        for (int j = 0; j < 4; ++j) acc[i][j] = f32x4{0.f, 0.f, 0.f, 0.f};

    // prologue: halves 0..5 (kt0 complete + B0,B1 of kt1 in flight)
    #pragma unroll
    for (int H = 0; H < 6; ++H) stageH(H);
    WAIT_BARRIER(4);                               // kt0 staged; 2 halves flying

    for (int kt = 0; kt < 16; ++kt) {
        const int bt = kt & 1;
        s16x8 bfr[4][2];
        #pragma unroll
        for (int q = 0; q < 4; ++q) {
            // ---- reads for THIS phase's MFMA (from kt's buffers)
            if (q == 0) {
                #pragma unroll
                for (int ni = 0; ni < 4; ++ni)
                    #pragma unroll
                    for (int ks = 0; ks < 2; ++ks) {
                        const int row = rbB + 16 * ni + r;
                        const int csw = (4 * ks + g) ^ rsw;
                        bfr[ni][ks] = *(const s16x8*)&LB[bt][hb][row * 64 + csw * 8];
                    }
            }
            s16x8 afr[2][2];
            #pragma unroll
            for (int m2 = 0; m2 < 2; ++m2)
                #pragma unroll
                for (int ks = 0; ks < 2; ++ks) {
                    const int row = 16 * (2 * q + m2) + r;
                    const int csw = (4 * ks + g) ^ rsw;
                    afr[m2][ks] = *(const s16x8*)&LA[bt][ha][row * 64 + csw * 8];
                }
            // ---- stage one half-tile, lead 6
            const int Hs = 4 * kt + q + 6;
            if (Hs < 64) stageH(Hs);
            // ---- barrier 1 (+ counted vmcnt at K-tile boundary)
            if (q == 3) {
                if (kt < 14)       { WAIT_BARRIER(4); }
                else if (kt == 14) { WAIT_BARRIER(0); }
                else               { BARRIER_ONLY(); }
            } else {
                BARRIER_ONLY();
            }
            asm volatile("s_waitcnt lgkmcnt(0)" ::: "memory");
            __builtin_amdgcn_sched_barrier(0);
            __builtin_amdgcn_s_setprio(1);
            #pragma unroll
            for (int m2 = 0; m2 < 2; ++m2)
                #pragma unroll
                for (int ni = 0; ni < 4; ++ni) {
                    acc[2 * q + m2][ni] = MFMA16(afr[m2][0], bfr[ni][0], acc[2 * q + m2][ni]);
                    acc[2 * q + m2][ni] = MFMA16(afr[m2][1], bfr[ni][1], acc[2 * q + m2][ni]);
                }
            __builtin_amdgcn_s_setprio(0);
            __builtin_amdgcn_sched_barrier(0);
            BARRIER_ONLY();                        // barrier 2
        }
    }

    // epilogue
    #pragma unroll
    for (int mf = 0; mf < 8; ++mf) {
        #pragma unroll
        for (int ni = 0; ni < 4; ++ni) {
            const int n = n0 + wn + 16 * ni + r;
            float mk = 1.f;
            if (mask) mk = (mask[n] != 0) ? 1.f : 0.f;
            #pragma unroll
            for (int i = 0; i < 4; ++i) {
                const int m = m0 + wm + 16 * mf + 4 * g + i;
                float v = acc[mf][ni][i] + (bias_on_n ? bias[n] : bias[m]);
                v *= scale * mk;
                Dp[(size_t)m * ldd + n] = f2bf(v);
            }
        }
    }
}

// ---------------------------------------------------------------------------
// 128x128 gemm core (r9-proven) — used for gemm_out only.
// ---------------------------------------------------------------------------
__device__ __forceinline__ void stage_slab(
    const u16* __restrict__ gA, const u16* __restrict__ gB,
    u16* lA, u16* lB, int k0, int wave, int lane)
{
    const int rw = lane >> 2, ch = lane & 3;
    const int sw = ((ch ^ ((rw >> 1) & 3)) * 8) + k0;
    const int r0 = 16 * wave + rw, r1 = r0 + 64;   // phi(r1) == phi(r0)
    glds16(gA + (size_t)r0 * C_ + sw, lA + (16 * wave) * 32);
    glds16(gA + (size_t)r1 * C_ + sw, lA + (64 + 16 * wave) * 32);
    glds16(gB + (size_t)r0 * C_ + sw, lB + (16 * wave) * 32);
    glds16(gB + (size_t)r1 * C_ + sw, lB + (64 + 16 * wave) * 32);
}

__global__ __launch_bounds__(256) void gemm_out_kernel(
    const u16* __restrict__ Wp, const u16* __restrict__ att,
    const float* __restrict__ bp, float* __restrict__ out, const int* __restrict__ qm)
{
    const int p = blockIdx.x;                      // 0..255
    const int lb = (p & 7) * 32 + (p >> 3);        // bijective (256 % 8 == 0)
    const int b = lb >> 6, yy = (lb >> 3) & 7, xx = lb & 7;
    const size_t off = (size_t)b * (1024 * 1024);
    const int m0 = yy * 128, n0 = xx * 128;
    const u16* A = Wp;
    const u16* B = att + off;
    float* D = out + off;
    const int* mask = qm + (size_t)b * T_;

    __shared__ __align__(16) u16 As[3][128 * 32];
    __shared__ __align__(16) u16 Bs[3][128 * 32];
    const int tid = threadIdx.x, lane = tid & 63, wave = tid >> 6;
    const int r = lane & 15, g = lane >> 4;
    const int wm = (wave >> 1) * 64, wn = (wave & 1) * 64;
    const u16* Ab = A + (size_t)m0 * C_;
    const u16* Bb = B + (size_t)n0 * C_;

    f32x4 acc[4][4];
    #pragma unroll
    for (int i = 0; i < 4; ++i)
        #pragma unroll
        for (int j = 0; j < 4; ++j) acc[i][j] = f32x4{0.f, 0.f, 0.f, 0.f};

    stage_slab(Ab, Bb, As[0], Bs[0], 0, wave, lane);
    stage_slab(Ab, Bb, As[1], Bs[1], 32, wave, lane);
    WAIT_BARRIER(4);

    const int swz = (g ^ ((r >> 1) & 3)) * 8;
    const int NK = C_ / 32;
    int cur = 0;
    for (int kk = 0; kk < NK; ++kk) {
        int pre = cur + 2; if (pre >= 3) pre -= 3;
        if (kk + 2 < NK)
            stage_slab(Ab, Bb, As[pre], Bs[pre], (kk + 2) * 32, wave, lane);
        s16x8 af[4], bf[4];
        #pragma unroll
        for (int mi = 0; mi < 4; ++mi)
            af[mi] = *(const s16x8*)&As[cur][(wm + 16 * mi + r) * 32 + swz];
        #pragma unroll
        for (int ni = 0; ni < 4; ++ni)
            bf[ni] = *(const s16x8*)&Bs[cur][(wn + 16 * ni + r) * 32 + swz];
        #pragma unroll
        for (int mi = 0; mi < 4; ++mi)
            #pragma unroll
            for (int ni = 0; ni < 4; ++ni)
                acc[mi][ni] = MFMA16(af[mi], bf[ni], acc[mi][ni]);
        if (kk + 1 < NK) {
            if (kk + 2 < NK) { WAIT_BARRIER(4); }
            else             { WAIT_BARRIER(0); }
        }
        cur = (cur == 2) ? 0 : cur + 1;
    }

    #pragma unroll
    for (int mi = 0; mi < 4; ++mi) {
        #pragma unroll
        for (int ni = 0; ni < 4; ++ni) {
            const int n = n0 + wn + 16 * ni + r;
            const float mk = (mask[n] != 0) ? 1.f : 0.f;
            #pragma unroll
            for (int i = 0; i < 4; ++i) {
                const int m = m0 + wm + 16 * mi + 4 * g + i;
                float v = (acc[mi][ni][i] + bp[m]) * mk;
                D[(size_t)m * 1024 + n] = v;
            }
        }
    }
}

// ---------------------------------------------------------------------------
// MFMA flash attention (r11 core; V now stored [C][b*T+t], rows stride 4096).
// ---------------------------------------------------------------------------
__global__ __launch_bounds__(256) void attn_mfma_kernel(
    const u16* __restrict__ Qt, const u16* __restrict__ Kt, const u16* __restrict__ Vb,
    u16* __restrict__ att)
{
    const int p = blockIdx.x;                      // 0..511
    const int lb = (p & 7) * 64 + (p >> 3);        // bijective (512 % 8 == 0)
    const int bh = lb >> 3, sblk = lb & 7;
    const int b = bh >> 4, h = bh & 15;
    const int lane = threadIdx.x & 63, wave = threadIdx.x >> 6;
    const int r = lane & 15, g = lane >> 4;
    const int hofs = h * 64;
    const int s0 = sblk * 128 + wave * 16;         // second tile at s0+64

    __shared__ __align__(16) u16 Ks[3][64 * 64];
    __shared__ __align__(16) u16 Vs[3][64 * 64];
    __shared__ __align__(16) u16 P_lds[4][2][16 * 72];

    const u16* qb0 = Qt + ((size_t)(b * T_ + s0 + r)) * C_ + hofs + g * 8;
    const s16x8 qf00 = *(const s16x8*)(qb0);
    const s16x8 qf01 = *(const s16x8*)(qb0 + 32);
    const s16x8 qf10 = *(const s16x8*)(qb0 + (size_t)64 * C_);
    const s16x8 qf11 = *(const s16x8*)(qb0 + (size_t)64 * C_ + 32);

    const int srow = lane >> 3, sch = lane & 7;
    const u16* kg = Kt + ((size_t)(b * T_)) * C_ + hofs;
    const u16* vg = Vb + (size_t)hofs * (B_ * T_) + b * T_;   // [C][b*t]

    auto stage = [&](int buf, int t0) {
        #pragma unroll
        for (int i = 0; i < 2; ++i) {
            const int rr = 16 * wave + 8 * i + srow;
            const int sw = (sch ^ (rr & 7)) * 8;
            glds16(kg + (size_t)(t0 + rr) * C_ + sw, &Ks[buf][(16 * wave + 8 * i) * 64]);
            glds16(vg + (size_t)rr * (B_ * T_) + t0 + sw, &Vs[buf][(16 * wave + 8 * i) * 64]);
        }
    };

    f32x4 acc0[4], acc1[4];
    #pragma unroll
    for (int ci = 0; ci < 4; ++ci) {
        acc0[ci] = f32x4{0.f, 0.f, 0.f, 0.f};
        acc1[ci] = f32x4{0.f, 0.f, 0.f, 0.f};
    }
    float l0 = 0.f, l1 = 0.f;
    u16* pw0 = &P_lds[wave][0][0];
    u16* pw1 = &P_lds[wave][1][0];

    stage(0, 0);
    stage(1, 64);
    WAIT_BARRIER(4);

    const int NT = T_ / 64;
    int cur = 0;
    for (int it = 0; it < NT; ++it) {
        int pre = cur + 2; if (pre >= 3) pre -= 3;
        if (it + 2 < NT) stage(pre, (it + 2) * 64);

        const u16* ks = Ks[cur];
        f32x4 st0[4], st1[4];
        #pragma unroll
        for (int tt = 0; tt < 4; ++tt) {
            const int row = (16 * tt + r) * 64;
            const s16x8 ka = *(const s16x8*)&ks[row + ((g ^ (r & 7)) * 8)];
            const s16x8 kb = *(const s16x8*)&ks[row + (((4 + g) ^ (r & 7)) * 8)];
            f32x4 sa = f32x4{0.f, 0.f, 0.f, 0.f};
            sa = MFMA16(ka, qf00, sa); sa = MFMA16(kb, qf01, sa); st0[tt] = sa;
            f32x4 sb = f32x4{0.f, 0.f, 0.f, 0.f};
            sb = MFMA16(ka, qf10, sb); sb = MFMA16(kb, qf11, sb); st1[tt] = sb;
        }

        #pragma unroll
        for (int tt = 0; tt < 4; ++tt) {
            float a0 = __ocml_native_exp2_f32(st0[tt][0]);
            float a1 = __ocml_native_exp2_f32(st0[tt][1]);
            float a2 = __ocml_native_exp2_f32(st0[tt][2]);
            float a3 = __ocml_native_exp2_f32(st0[tt][3]);
            l0 += (a0 + a1) + (a2 + a3);
            uint2 pk;
            pk.x = (unsigned)f2bf(a0) | ((unsigned)f2bf(a1) << 16);
            pk.y = (unsigned)f2bf(a2) | ((unsigned)f2bf(a3) << 16);
            *(uint2*)&pw0[r * 72 + 16 * tt + 4 * g] = pk;
            float b0 = __ocml_native_exp2_f32(st1[tt][0]);
            float b1 = __ocml_native_exp2_f32(st1[tt][1]);
            float b2 = __ocml_native_exp2_f32(st1[tt][2]);
            float b3 = __ocml_native_exp2_f32(st1[tt][3]);
            l1 += (b0 + b1) + (b2 + b3);
            pk.x = (unsigned)f2bf(b0) | ((unsigned)f2bf(b1) << 16);
            pk.y = (unsigned)f2bf(b2) | ((unsigned)f2bf(b3) << 16);
            *(uint2*)&pw1[r * 72 + 16 * tt + 4 * g] = pk;
        }

        const u16* vs = Vs[cur];
        #pragma unroll
        for (int kk = 0; kk < 2; ++kk) {
            const s16x8 pa0 = *(const s16x8*)&pw0[r * 72 + 32 * kk + 8 * g];
            const s16x8 pa1 = *(const s16x8*)&pw1[r * 72 + 32 * kk + 8 * g];
            #pragma unroll
            for (int ci = 0; ci < 4; ++ci) {
                const s16x8 vf = *(const s16x8*)
                    &vs[(16 * ci + r) * 64 + (((4 * kk + g) ^ (r & 7)) * 8)];
                acc0[ci] = MFMA16(pa0, vf, acc0[ci]);
                acc1[ci] = MFMA16(pa1, vf, acc1[ci]);
            }
        }

        if (it + 1 < NT) {
            if (it + 2 < NT) { WAIT_BARRIER(4); }
            else             { WAIT_BARRIER(0); }
        }
        cur = (cur == 2) ? 0 : cur + 1;
    }

    l0 += __shfl_xor(l0, 16); l0 += __shfl_xor(l0, 32);
    l1 += __shfl_xor(l1, 16); l1 += __shfl_xor(l1, 32);
    const float inv0 = 1.f / l0, inv1 = 1.f / l1;
    const float i00 = __shfl(inv0, 4 * g + 0), i01 = __shfl(inv0, 4 * g + 1);
    const float i02 = __shfl(inv0, 4 * g + 2), i03 = __shfl(inv0, 4 * g + 3);
    const float i10 = __shfl(inv1, 4 * g + 0), i11 = __shfl(inv1, 4 * g + 1);
    const float i12 = __shfl(inv1, 4 * g + 2), i13 = __shfl(inv1, 4 * g + 3);

    u16* ob = att + ((size_t)(b * T_ + s0 + 4 * g)) * C_ + hofs + r;
    #pragma unroll
    for (int ci = 0; ci < 4; ++ci) {
        ob[(size_t)0 * C_ + ci * 16] = f2bf(acc0[ci][0] * i00);
        ob[(size_t)1 * C_ + ci * 16] = f2bf(acc0[ci][1] * i01);
        ob[(size_t)2 * C_ + ci * 16] = f2bf(acc0[ci][2] * i02);
        ob[(size_t)3 * C_ + ci * 16] = f2bf(acc0[ci][3] * i03);
    }
    u16* ob1 = ob + (size_t)64 * C_;
    #pragma unroll
    for (int ci = 0; ci < 4; ++ci) {
        ob1[(size_t)0 * C_ + ci * 16] = f2bf(acc1[ci][0] * i10);
        ob1[(size_t)1 * C_ + ci * 16] = f2bf(acc1[ci][1] * i11);
        ob1[(size_t)2 * C_ + ci * 16] = f2bf(acc1[ci][2] * i12);
        ob1[(size_t)3 * C_ + ci * 16] = f2bf(acc1[ci][3] * i13);
    }
}

// ---------------------------------------------------------------------------
extern "C" void kernel_launch(void* const* d_in, const int* in_sizes, int n_in,
                              void* d_out, int out_size, void* d_ws, size_t ws_size,
                              hipStream_t stream)
{
    const float* query = (const float*)d_in[0];
    const float* key_  = (const float*)d_in[1];
    const float* value = (const float*)d_in[2];
    const int* qm  = (const int*)d_in[3];
    const int* kvm = (const int*)d_in[4];
    const float* qconv = (const float*)d_in[5];
    const float* kconv = (const float*)d_in[6];
    const float* vconv = (const float*)d_in[7];
    const float* qnw = (const float*)d_in[8];
    const float* qnb = (const float*)d_in[9];
    const float* knw = (const float*)d_in[10];
    const float* knb = (const float*)d_in[11];
    const float* vnw = (const float*)d_in[12];
    const float* vnb = (const float*)d_in[13];
    const float* wq = (const float*)d_in[14];
    const float* bq = (const float*)d_in[15];
    const float* wk = (const float*)d_in[16];
    const float* bk = (const float*)d_in[17];
    const float* wv = (const float*)d_in[18];
    const float* bv = (const float*)d_in[19];
    const float* wp = (const float*)d_in[20];
    const float* bp = (const float*)d_in[21];

    const size_t MB = 1024 * 1024;
    char* W = (char*)d_ws;
    u16* Xq  = (u16*)(W + 0 * MB);     // LN'd, transposed [b*t][C] bf16
    u16* Xk  = (u16*)(W + 8 * MB);
    u16* Xv  = (u16*)(W + 16 * MB);
    u16* Qt  = (u16*)(W + 24 * MB);    // [b*t][C] (pre-scaled by log2e/8)
    u16* Kt  = (u16*)(W + 32 * MB);    // [b*t][C]
    u16* Vb_ = (u16*)(W + 40 * MB);    // [C][b*t] (kv-masked)
    u16* att_ = (u16*)(W + 48 * MB);   // [b*t][C]
    u16* wqb = (u16*)(W + 56 * MB);
    u16* wkb = (u16*)(W + 58 * MB);
    u16* wvb = (u16*)(W + 60 * MB);
    u16* wpb = (u16*)(W + 62 * MB);

    int ntail = out_size - BCT;
    if (ntail < 0) ntail = 0;

    prep_kernel<<<dim3(2440), 512, 0, stream>>>(
        query, key_, value, qconv, kconv, vconv, qm, kvm,
        qnw, qnb, knw, knb, vnw, vnb, Xq, Xk, Xv,
        wq, wk, wv, wp, wqb, wkb, wvb, wpb,
        (float*)d_out + BCT, ntail);

    gemm_qkv256_kernel<<<dim3(192), 512, 0, stream>>>(
        Xq, Xk, Xv, wqb, wkb, wvb, bq, bk, bv, Qt, Kt, Vb_, kvm);

    attn_mfma_kernel<<<dim3(512), 256, 0, stream>>>(Qt, Kt, Vb_, att_);

    gemm_out_kernel<<<dim3(256), 256, 0, stream>>>(wpb, att_, bp, (float*)d_out, qm);
}

// Round 13
// 119.646 us; speedup vs baseline: 1.0506x; 1.0506x over previous
//
#include <hip/hip_runtime.h>
#include <math.h>

#define B_ 4
#define C_ 1024
#define T_ 1024
#define H_ 16
#define CH_ 64
#define BCT (B_ * C_ * T_)   // 4194304

typedef __attribute__((ext_vector_type(8))) short s16x8;   // 8 bf16 (4 VGPRs)
typedef __attribute__((ext_vector_type(4))) float f32x4;
typedef unsigned short u16;

#define MFMA16(a, b, c) __builtin_amdgcn_mfma_f32_16x16x32_bf16((a), (b), (c), 0, 0, 0)

extern "C" __device__ float __ocml_native_exp2_f32(float);

__device__ __forceinline__ u16 f2bf(float f) {
    union { float f; unsigned u; } v; v.f = f;
    unsigned r = (v.u + 0x7fffu + ((v.u >> 16) & 1u)) >> 16;   // RNE
    return (u16)r;
}
__device__ __forceinline__ float bf2f(u16 h) {
    union { unsigned u; float f; } v; v.u = (unsigned)h << 16; return v.f;
}

// async global->LDS, 16B per lane; LDS dest = wave-uniform base + lane*16
typedef __attribute__((address_space(3))) unsigned int lds_u32;
typedef __attribute__((address_space(1))) const unsigned int glb_u32;
__device__ __forceinline__ void glds16(const void* g, const void* l_wave_uniform) {
    __builtin_amdgcn_global_load_lds(
        (glb_u32*)(unsigned long long)g,
        (lds_u32*)(unsigned long long)l_wave_uniform, 16, 0, 0);
}

// counted-vmcnt barrier: keep N loads in flight across the barrier (T4)
#define WAIT_BARRIER(N)                                   \
    asm volatile("s_waitcnt vmcnt(" #N ")" ::: "memory"); \
    __builtin_amdgcn_s_barrier();                         \
    __builtin_amdgcn_sched_barrier(0)

// ---------------------------------------------------------------------------
// prep_kernel: lnT (384) + wcvt (2048) + mask_tail (8) in one launch.
// ---------------------------------------------------------------------------
__global__ __launch_bounds__(512) void prep_kernel(
    const float* __restrict__ xq, const float* __restrict__ xk, const float* __restrict__ xv,
    const float* __restrict__ wq3, const float* __restrict__ wk3, const float* __restrict__ wv3,
    const int* __restrict__ qm, const int* __restrict__ kvm,
    const float* __restrict__ qnw, const float* __restrict__ qnb,
    const float* __restrict__ knw, const float* __restrict__ knb,
    const float* __restrict__ vnw, const float* __restrict__ vnb,
    u16* __restrict__ oq, u16* __restrict__ ok, u16* __restrict__ ov,
    const float* __restrict__ w0, const float* __restrict__ w1,
    const float* __restrict__ w2, const float* __restrict__ w3,
    u16* __restrict__ o0, u16* __restrict__ o1, u16* __restrict__ o2, u16* __restrict__ o3,
    float* __restrict__ tail_out, int ntail)
{
    __shared__ __align__(16) u16 tile[32 * 1032];     // [t][c], stride 2064B
    __shared__ float red1[16][33], red2[16][33];
    __shared__ float musL[32], rssL[32];

    const int bid = blockIdx.x;
    if (bid >= 384) {
        if (bid >= 2432) {                              // ---- mask_tail
            int i = (bid - 2432) * 512 + threadIdx.x;
            if (i < ntail) tail_out[i] = (qm[i] != 0) ? 1.f : 0.f;
            return;
        }
        // ---- wcvt: 512 blocks per matrix, 4 floats/thread
        const int b2 = bid - 384;
        const int mat = b2 >> 9;
        const float* __restrict__ w = (mat == 0) ? w0 : (mat == 1) ? w1 : (mat == 2) ? w2 : w3;
        u16* __restrict__ o = (mat == 0) ? o0 : (mat == 1) ? o1 : (mat == 2) ? o2 : o3;
        const int i = ((b2 & 511) * 512 + threadIdx.x) * 4;
        float4 v = *(const float4*)&w[i];
        uint2 p;
        p.x = (unsigned)f2bf(v.x) | ((unsigned)f2bf(v.y) << 16);
        p.y = (unsigned)f2bf(v.z) | ((unsigned)f2bf(v.w) << 16);
        *(uint2*)&o[i] = p;
        return;
    }

    // ---- lnT: fused dwconv(k=3,pad=1)+mask -> channel-LN -> transpose bf16
    const int z = bid >> 5;                 // tensor*4 + b
    const int tensor = z >> 2, b = z & 3;
    const float* __restrict__ x   = (tensor == 0) ? xq  : (tensor == 1) ? xk  : xv;
    const float* __restrict__ w3c = (tensor == 0) ? wq3 : (tensor == 1) ? wk3 : wv3;
    const int* __restrict__ msk   = (tensor == 0) ? qm  : kvm;
    const float* __restrict__ wln = (tensor == 0) ? qnw : (tensor == 1) ? knw : vnw;
    const float* __restrict__ bln = (tensor == 0) ? qnb : (tensor == 1) ? knb : vnb;
    u16* __restrict__ xt = (tensor == 0) ? oq : (tensor == 1) ? ok : ov;

    const int t0 = (bid & 31) * 32;

    const int tl = threadIdx.x & 31, cs = threadIdx.x >> 5;   // cs 0..15
    const int t = t0 + tl;
    const float mk = (msk[b * T_ + t] != 0) ? 1.f : 0.f;

    float s1 = 0.f, s2 = 0.f;
    #pragma unroll 4
    for (int i = 0; i < 32; ++i) {
        const int c = 2 * (cs + 16 * i);
        const float* xr0 = x + ((size_t)(b * C_ + c)) * T_ + t;
        const float* xr1 = xr0 + T_;
        float xc0 = xr0[0];
        float xm0 = (t > 0)      ? xr0[-1] : 0.f;
        float xp0 = (t < T_ - 1) ? xr0[1]  : 0.f;
        float v0 = (w3c[3 * c + 0] * xm0 + w3c[3 * c + 1] * xc0 + w3c[3 * c + 2] * xp0) * mk;
        float xc1 = xr1[0];
        float xm1 = (t > 0)      ? xr1[-1] : 0.f;
        float xp1 = (t < T_ - 1) ? xr1[1]  : 0.f;
        float v1 = (w3c[3 * c + 3] * xm1 + w3c[3 * c + 4] * xc1 + w3c[3 * c + 5] * xp1) * mk;
        s1 += v0 + v1;
        s2 += v0 * v0 + v1 * v1;
        *(unsigned*)&tile[tl * 1032 + c] =
            (unsigned)f2bf(v0) | ((unsigned)f2bf(v1) << 16);
    }
    red1[cs][tl] = s1;
    red2[cs][tl] = s2;
    __syncthreads();
    if (threadIdx.x < 32) {
        float a = 0.f, q2 = 0.f;
        #pragma unroll
        for (int i = 0; i < 16; ++i) { a += red1[i][threadIdx.x]; q2 += red2[i][threadIdx.x]; }
        float m_  = a  * (1.f / C_);
        float var = q2 * (1.f / C_) - m_ * m_;
        musL[threadIdx.x] = m_;
        rssL[threadIdx.x] = rsqrtf(var + 1e-5f);
    }
    __syncthreads();

    #pragma unroll
    for (int it = 0; it < 8; ++it) {
        const int idx = it * 512 + threadIdx.x;
        const int tt = idx >> 7, c0 = (idx & 127) * 8;
        const s16x8 pv = *(const s16x8*)&tile[tt * 1032 + c0];
        const float m_ = musL[tt], rv = rssL[tt];
        const float4 w0v = *(const float4*)&wln[c0];
        const float4 w1v = *(const float4*)&wln[c0 + 4];
        const float4 b0v = *(const float4*)&bln[c0];
        const float4 b1v = *(const float4*)&bln[c0 + 4];
        uint4 o;
        float f0, f1;
        f0 = (bf2f((u16)pv[0]) - m_) * rv * w0v.x + b0v.x;
        f1 = (bf2f((u16)pv[1]) - m_) * rv * w0v.y + b0v.y;
        o.x = (unsigned)f2bf(f0) | ((unsigned)f2bf(f1) << 16);
        f0 = (bf2f((u16)pv[2]) - m_) * rv * w0v.z + b0v.z;
        f1 = (bf2f((u16)pv[3]) - m_) * rv * w0v.w + b0v.w;
        o.y = (unsigned)f2bf(f0) | ((unsigned)f2bf(f1) << 16);
        f0 = (bf2f((u16)pv[4]) - m_) * rv * w1v.x + b1v.x;
        f1 = (bf2f((u16)pv[5]) - m_) * rv * w1v.y + b1v.y;
        o.z = (unsigned)f2bf(f0) | ((unsigned)f2bf(f1) << 16);
        f0 = (bf2f((u16)pv[6]) - m_) * rv * w1v.z + b1v.z;
        f1 = (bf2f((u16)pv[7]) - m_) * rv * w1v.w + b1v.w;
        o.w = (unsigned)f2bf(f0) | ((unsigned)f2bf(f1) << 16);
        *(uint4*)&xt[((size_t)(b * T_ + t0 + tt)) * C_ + c0] = o;
    }
}

// ---------------------------------------------------------------------------
// bf16 MFMA GEMM (NT), 128x128 tile, BK=32 (proven core):
// 3-buffer global_load_lds pipeline, counted vmcnt(4), XOR chunk swizzle
// phi(row)=(row>>1)&3 both-sides.  m0/n0 passed in (XCD-chunked 1-D grids).
// ---------------------------------------------------------------------------
__device__ __forceinline__ void stage_slab(
    const u16* __restrict__ gA, const u16* __restrict__ gB,
    u16* lA, u16* lB, int k0, int wave, int lane)
{
    const int rw = lane >> 2, ch = lane & 3;
    const int sw = ((ch ^ ((rw >> 1) & 3)) * 8) + k0;
    const int r0 = 16 * wave + rw, r1 = r0 + 64;   // phi(r1) == phi(r0)
    glds16(gA + (size_t)r0 * C_ + sw, lA + (16 * wave) * 32);
    glds16(gA + (size_t)r1 * C_ + sw, lA + (64 + 16 * wave) * 32);
    glds16(gB + (size_t)r0 * C_ + sw, lB + (16 * wave) * 32);
    glds16(gB + (size_t)r1 * C_ + sw, lB + (64 + 16 * wave) * 32);
}

template<int OUT_BF16>
__device__ __forceinline__ void gemm_core(
    const u16* __restrict__ A, const u16* __restrict__ B, void* __restrict__ D,
    const float* __restrict__ bias, const int* __restrict__ mask,
    float scale, int bias_on_n, int m0, int n0)
{
    __shared__ __align__(16) u16 As[3][128 * 32];
    __shared__ __align__(16) u16 Bs[3][128 * 32];
    const int tid = threadIdx.x, lane = tid & 63, wave = tid >> 6;
    const int r = lane & 15, g = lane >> 4;
    const int wm = (wave >> 1) * 64, wn = (wave & 1) * 64;
    const u16* Ab = A + (size_t)m0 * C_;
    const u16* Bb = B + (size_t)n0 * C_;

    f32x4 acc[4][4];
    #pragma unroll
    for (int i = 0; i < 4; ++i)
        #pragma unroll
        for (int j = 0; j < 4; ++j) acc[i][j] = f32x4{0.f, 0.f, 0.f, 0.f};

    stage_slab(Ab, Bb, As[0], Bs[0], 0, wave, lane);
    stage_slab(Ab, Bb, As[1], Bs[1], 32, wave, lane);
    WAIT_BARRIER(4);

    const int swz = (g ^ ((r >> 1) & 3)) * 8;
    const int NK = C_ / 32;
    int cur = 0;
    for (int kk = 0; kk < NK; ++kk) {
        int pre = cur + 2; if (pre >= 3) pre -= 3;
        if (kk + 2 < NK)
            stage_slab(Ab, Bb, As[pre], Bs[pre], (kk + 2) * 32, wave, lane);
        s16x8 af[4], bf[4];
        #pragma unroll
        for (int mi = 0; mi < 4; ++mi)
            af[mi] = *(const s16x8*)&As[cur][(wm + 16 * mi + r) * 32 + swz];
        #pragma unroll
        for (int ni = 0; ni < 4; ++ni)
            bf[ni] = *(const s16x8*)&Bs[cur][(wn + 16 * ni + r) * 32 + swz];
        #pragma unroll
        for (int mi = 0; mi < 4; ++mi)
            #pragma unroll
            for (int ni = 0; ni < 4; ++ni)
                acc[mi][ni] = MFMA16(af[mi], bf[ni], acc[mi][ni]);
        if (kk + 1 < NK) {
            if (kk + 2 < NK) { WAIT_BARRIER(4); }
            else             { WAIT_BARRIER(0); }
        }
        cur = (cur == 2) ? 0 : cur + 1;
    }

    #pragma unroll
    for (int mi = 0; mi < 4; ++mi) {
        #pragma unroll
        for (int ni = 0; ni < 4; ++ni) {
            const int n = n0 + wn + 16 * ni + r;
            float mk = 1.f;
            if (mask) mk = (mask[n] != 0) ? 1.f : 0.f;
            #pragma unroll
            for (int i = 0; i < 4; ++i) {
                const int m = m0 + wm + 16 * mi + 4 * g + i;
                float v = acc[mi][ni][i] + (bias_on_n ? bias[n] : bias[m]);
                v *= scale * mk;
                size_t o = (size_t)m * 1024 + n;
                if (OUT_BF16) ((u16*)D)[o] = f2bf(v);
                else          ((float*)D)[o] = v;
            }
        }
    }
}

// merged Q/K/V projection, 1-D grid 768, XCD-chunked remap (T1)
__global__ __launch_bounds__(256) void gemm_qkv_kernel(
    const u16* __restrict__ Xq, const u16* __restrict__ Xk, const u16* __restrict__ Xv,
    const u16* __restrict__ Wq, const u16* __restrict__ Wk, const u16* __restrict__ Wv,
    const float* __restrict__ bq, const float* __restrict__ bk, const float* __restrict__ bv,
    u16* __restrict__ Qt, u16* __restrict__ Kt, u16* __restrict__ Vb, const int* __restrict__ kvm)
{
    const int p = blockIdx.x;                      // 0..767
    const int lb = (p & 7) * 96 + (p >> 3);        // bijective (768 % 8 == 0)
    const int z = lb >> 6, yy = (lb >> 3) & 7, xx = lb & 7;
    const int tensor = z >> 2, b = z & 3;
    const size_t off = (size_t)b * (1024 * 1024);
    // Q is pre-scaled by 1/8 * log2(e) so attention computes exp2 directly.
    const float qscale = 0.125f * 1.44269504088896340736f;
    const u16* A = (tensor == 0) ? Xq + off : (tensor == 1) ? Xk + off : Wv;
    const u16* B = (tensor == 0) ? Wq       : (tensor == 1) ? Wk       : Xv + off;
    u16*       D = (tensor == 0) ? Qt + off : (tensor == 1) ? Kt + off : Vb + off;
    const float* bias = (tensor == 0) ? bq : (tensor == 1) ? bk : bv;
    const int* mask = (tensor == 2) ? kvm + (size_t)b * T_ : nullptr;
    gemm_core<1>(A, B, D, bias, mask, (tensor == 0) ? qscale : 1.f, tensor != 2,
                 yy * 128, xx * 128);
}

// out-GEMM, 1-D grid 256, XCD-chunked remap
__global__ __launch_bounds__(256) void gemm_out_kernel(
    const u16* __restrict__ Wp, const u16* __restrict__ att,
    const float* __restrict__ bp, float* __restrict__ out, const int* __restrict__ qm)
{
    const int p = blockIdx.x;                      // 0..255
    const int lb = (p & 7) * 32 + (p >> 3);        // bijective (256 % 8 == 0)
    const int b = lb >> 6, yy = (lb >> 3) & 7, xx = lb & 7;
    const size_t off = (size_t)b * (1024 * 1024);
    gemm_core<0>(Wp, att + off, out + off, bp, qm + (size_t)b * T_, 1.f, 0,
                 yy * 128, xx * 128);
}

// ---------------------------------------------------------------------------
// MFMA flash attention: 3-buffer K/V staging, counted vmcnt(4), no
// max-tracking, per-lane l.  1-D grid 512, XCD-chunked remap.
// T5: s_setprio(1) around the MFMA clusters (QK^T and PV) — independent
// 4-wave blocks at different phases, the regime where setprio pays (m191).
// ---------------------------------------------------------------------------
__global__ __launch_bounds__(256) void attn_mfma_kernel(
    const u16* __restrict__ Qt, const u16* __restrict__ Kt, const u16* __restrict__ Vb,
    u16* __restrict__ att)
{
    const int p = blockIdx.x;                      // 0..511
    const int lb = (p & 7) * 64 + (p >> 3);        // bijective (512 % 8 == 0)
    const int bh = lb >> 3, sblk = lb & 7;
    const int b = bh >> 4, h = bh & 15;
    const int lane = threadIdx.x & 63, wave = threadIdx.x >> 6;
    const int r = lane & 15, g = lane >> 4;
    const int hofs = h * 64;
    const int s0 = sblk * 128 + wave * 16;         // second tile at s0+64

    __shared__ __align__(16) u16 Ks[3][64 * 64];
    __shared__ __align__(16) u16 Vs[3][64 * 64];
    __shared__ __align__(16) u16 P_lds[4][2][16 * 72];

    const u16* qb0 = Qt + ((size_t)(b * T_ + s0 + r)) * C_ + hofs + g * 8;
    const s16x8 qf00 = *(const s16x8*)(qb0);
    const s16x8 qf01 = *(const s16x8*)(qb0 + 32);
    const s16x8 qf10 = *(const s16x8*)(qb0 + (size_t)64 * C_);
    const s16x8 qf11 = *(const s16x8*)(qb0 + (size_t)64 * C_ + 32);

    const int srow = lane >> 3, sch = lane & 7;
    const u16* kg = Kt + ((size_t)(b * T_)) * C_ + hofs;
    const u16* vg = Vb + ((size_t)(b * C_ + hofs)) * T_;

    auto stage = [&](int buf, int t0) {
        #pragma unroll
        for (int i = 0; i < 2; ++i) {
            const int rr = 16 * wave + 8 * i + srow;
            const int sw = (sch ^ (rr & 7)) * 8;
            glds16(kg + (size_t)(t0 + rr) * C_ + sw, &Ks[buf][(16 * wave + 8 * i) * 64]);
            glds16(vg + (size_t)rr * T_ + t0 + sw,   &Vs[buf][(16 * wave + 8 * i) * 64]);
        }
    };

    f32x4 acc0[4], acc1[4];
    #pragma unroll
    for (int ci = 0; ci < 4; ++ci) {
        acc0[ci] = f32x4{0.f, 0.f, 0.f, 0.f};
        acc1[ci] = f32x4{0.f, 0.f, 0.f, 0.f};
    }
    float l0 = 0.f, l1 = 0.f;
    u16* pw0 = &P_lds[wave][0][0];
    u16* pw1 = &P_lds[wave][1][0];

    stage(0, 0);
    stage(1, 64);
    WAIT_BARRIER(4);

    const int NT = T_ / 64;
    int cur = 0;
    for (int it = 0; it < NT; ++it) {
        int pre = cur + 2; if (pre >= 3) pre -= 3;
        if (it + 2 < NT) stage(pre, (it + 2) * 64);

        const u16* ks = Ks[cur];
        f32x4 st0[4], st1[4];
        __builtin_amdgcn_s_setprio(1);
        #pragma unroll
        for (int tt = 0; tt < 4; ++tt) {
            const int row = (16 * tt + r) * 64;
            const s16x8 ka = *(const s16x8*)&ks[row + ((g ^ (r & 7)) * 8)];
            const s16x8 kb = *(const s16x8*)&ks[row + (((4 + g) ^ (r & 7)) * 8)];
            f32x4 sa = f32x4{0.f, 0.f, 0.f, 0.f};
            sa = MFMA16(ka, qf00, sa); sa = MFMA16(kb, qf01, sa); st0[tt] = sa;
            f32x4 sb = f32x4{0.f, 0.f, 0.f, 0.f};
            sb = MFMA16(ka, qf10, sb); sb = MFMA16(kb, qf11, sb); st1[tt] = sb;
        }
        __builtin_amdgcn_s_setprio(0);

        #pragma unroll
        for (int tt = 0; tt < 4; ++tt) {
            float a0 = __ocml_native_exp2_f32(st0[tt][0]);
            float a1 = __ocml_native_exp2_f32(st0[tt][1]);
            float a2 = __ocml_native_exp2_f32(st0[tt][2]);
            float a3 = __ocml_native_exp2_f32(st0[tt][3]);
            l0 += (a0 + a1) + (a2 + a3);
            uint2 pk;
            pk.x = (unsigned)f2bf(a0) | ((unsigned)f2bf(a1) << 16);
            pk.y = (unsigned)f2bf(a2) | ((unsigned)f2bf(a3) << 16);
            *(uint2*)&pw0[r * 72 + 16 * tt + 4 * g] = pk;
            float b0 = __ocml_native_exp2_f32(st1[tt][0]);
            float b1 = __ocml_native_exp2_f32(st1[tt][1]);
            float b2 = __ocml_native_exp2_f32(st1[tt][2]);
            float b3 = __ocml_native_exp2_f32(st1[tt][3]);
            l1 += (b0 + b1) + (b2 + b3);
            pk.x = (unsigned)f2bf(b0) | ((unsigned)f2bf(b1) << 16);
            pk.y = (unsigned)f2bf(b2) | ((unsigned)f2bf(b3) << 16);
            *(uint2*)&pw1[r * 72 + 16 * tt + 4 * g] = pk;
        }

        const u16* vs = Vs[cur];
        __builtin_amdgcn_s_setprio(1);
        #pragma unroll
        for (int kk = 0; kk < 2; ++kk) {
            const s16x8 pa0 = *(const s16x8*)&pw0[r * 72 + 32 * kk + 8 * g];
            const s16x8 pa1 = *(const s16x8*)&pw1[r * 72 + 32 * kk + 8 * g];
            #pragma unroll
            for (int ci = 0; ci < 4; ++ci) {
                const s16x8 vf = *(const s16x8*)
                    &vs[(16 * ci + r) * 64 + (((4 * kk + g) ^ (r & 7)) * 8)];
                acc0[ci] = MFMA16(pa0, vf, acc0[ci]);
                acc1[ci] = MFMA16(pa1, vf, acc1[ci]);
            }
        }
        __builtin_amdgcn_s_setprio(0);

        if (it + 1 < NT) {
            if (it + 2 < NT) { WAIT_BARRIER(4); }
            else             { WAIT_BARRIER(0); }
        }
        cur = (cur == 2) ? 0 : cur + 1;
    }

    l0 += __shfl_xor(l0, 16); l0 += __shfl_xor(l0, 32);
    l1 += __shfl_xor(l1, 16); l1 += __shfl_xor(l1, 32);
    const float inv0 = 1.f / l0, inv1 = 1.f / l1;
    const float i00 = __shfl(inv0, 4 * g + 0), i01 = __shfl(inv0, 4 * g + 1);
    const float i02 = __shfl(inv0, 4 * g + 2), i03 = __shfl(inv0, 4 * g + 3);
    const float i10 = __shfl(inv1, 4 * g + 0), i11 = __shfl(inv1, 4 * g + 1);
    const float i12 = __shfl(inv1, 4 * g + 2), i13 = __shfl(inv1, 4 * g + 3);

    u16* ob = att + ((size_t)(b * T_ + s0 + 4 * g)) * C_ + hofs + r;
    #pragma unroll
    for (int ci = 0; ci < 4; ++ci) {
        ob[(size_t)0 * C_ + ci * 16] = f2bf(acc0[ci][0] * i00);
        ob[(size_t)1 * C_ + ci * 16] = f2bf(acc0[ci][1] * i01);
        ob[(size_t)2 * C_ + ci * 16] = f2bf(acc0[ci][2] * i02);
        ob[(size_t)3 * C_ + ci * 16] = f2bf(acc0[ci][3] * i03);
    }
    u16* ob1 = ob + (size_t)64 * C_;
    #pragma unroll
    for (int ci = 0; ci < 4; ++ci) {
        ob1[(size_t)0 * C_ + ci * 16] = f2bf(acc1[ci][0] * i10);
        ob1[(size_t)1 * C_ + ci * 16] = f2bf(acc1[ci][1] * i11);
        ob1[(size_t)2 * C_ + ci * 16] = f2bf(acc1[ci][2] * i12);
        ob1[(size_t)3 * C_ + ci * 16] = f2bf(acc1[ci][3] * i13);
    }
}

// ---------------------------------------------------------------------------
extern "C" void kernel_launch(void* const* d_in, const int* in_sizes, int n_in,
                              void* d_out, int out_size, void* d_ws, size_t ws_size,
                              hipStream_t stream)
{
    const float* query = (const float*)d_in[0];
    const float* key_  = (const float*)d_in[1];
    const float* value = (const float*)d_in[2];
    const int* qm  = (const int*)d_in[3];
    const int* kvm = (const int*)d_in[4];
    const float* qconv = (const float*)d_in[5];
    const float* kconv = (const float*)d_in[6];
    const float* vconv = (const float*)d_in[7];
    const float* qnw = (const float*)d_in[8];
    const float* qnb = (const float*)d_in[9];
    const float* knw = (const float*)d_in[10];
    const float* knb = (const float*)d_in[11];
    const float* vnw = (const float*)d_in[12];
    const float* vnb = (const float*)d_in[13];
    const float* wq = (const float*)d_in[14];
    const float* bq = (const float*)d_in[15];
    const float* wk = (const float*)d_in[16];
    const float* bk = (const float*)d_in[17];
    const float* wv = (const float*)d_in[18];
    const float* bv = (const float*)d_in[19];
    const float* wp = (const float*)d_in[20];
    const float* bp = (const float*)d_in[21];

    const size_t MB = 1024 * 1024;
    char* W = (char*)d_ws;
    u16* Xq  = (u16*)(W + 0 * MB);     // LN'd, transposed [b][t][C] bf16
    u16* Xk  = (u16*)(W + 8 * MB);
    u16* Xv  = (u16*)(W + 16 * MB);
    u16* Qt  = (u16*)(W + 24 * MB);    // [b][t][C] (pre-scaled by log2e/8)
    u16* Kt  = (u16*)(W + 32 * MB);    // [b][t][C]
    u16* Vb_ = (u16*)(W + 40 * MB);    // [b][C][t] (kv-masked)
    u16* att_ = (u16*)(W + 48 * MB);   // [b][t][C]
    u16* wqb = (u16*)(W + 56 * MB);
    u16* wkb = (u16*)(W + 58 * MB);
    u16* wvb = (u16*)(W + 60 * MB);
    u16* wpb = (u16*)(W + 62 * MB);

    int ntail = out_size - BCT;
    if (ntail < 0) ntail = 0;

    prep_kernel<<<dim3(2440), 512, 0, stream>>>(
        query, key_, value, qconv, kconv, vconv, qm, kvm,
        qnw, qnb, knw, knb, vnw, vnb, Xq, Xk, Xv,
        wq, wk, wv, wp, wqb, wkb, wvb, wpb,
        (float*)d_out + BCT, ntail);

    gemm_qkv_kernel<<<dim3(768), 256, 0, stream>>>(
        Xq, Xk, Xv, wqb, wkb, wvb, bq, bk, bv, Qt, Kt, Vb_, kvm);

    attn_mfma_kernel<<<dim3(512), 256, 0, stream>>>(Qt, Kt, Vb_, att_);

    gemm_out_kernel<<<dim3(256), 256, 0, stream>>>(wpb, att_, bp, (float*)d_out, qm);
}